// Round 2
// baseline (361.428 us; speedup 1.0000x reference)
//
#include <hip/hip_runtime.h>
#include <hip/hip_bf16.h>
#include <math.h>

#define NN 30000
#define EE 400000
#define INP 128
#define HH 4
#define DD 64
#define CC 40
#define HD 256   // H*D
#define HC 160   // H*C
#define NBLK 118 // ceil(NN/256)

typedef unsigned short ushort;
typedef __attribute__((ext_vector_type(8))) short s8v;   // 8 x bf16 bits (4 VGPRs)
typedef __attribute__((ext_vector_type(4))) float f4v;   // MFMA accumulator
typedef __attribute__((ext_vector_type(2))) float f2;    // packed f32 pair -> v_pk_*_f32

// Inputs: fp32 storage holding bf16-rounded values (established r1-r4).

__device__ inline ushort bf16_of_float(float f) {
    __hip_bfloat16 b = __float2bfloat16(f);
    return *(ushort*)&b;
}
__device__ __forceinline__ float b2f(ushort u) { return __uint_as_float(((unsigned)u) << 16); }

// dword holding 2 packed bf16 -> native <2 x float> (low half, high half)
__device__ __forceinline__ f2 cvt2v(unsigned d) {
    f2 r;
    r.x = __uint_as_float(d << 16);
    r.y = __uint_as_float(d & 0xFFFF0000u);
    return r;
}
__device__ __forceinline__ f2 splat2(float s) { f2 r = {s, s}; return r; }
__device__ __forceinline__ f2 f2fmav(f2 a, f2 b, f2 c) {
#if __has_builtin(__builtin_elementwise_fma)
    return __builtin_elementwise_fma(a, b, c);
#else
    f2 r; r.x = __fmaf_rn(a.x, b.x, c.x); r.y = __fmaf_rn(a.y, b.y, c.y); return r;
#endif
}
__device__ __forceinline__ f2 f2maxv(f2 a, f2 b) {
#if __has_builtin(__builtin_elementwise_max)
    return __builtin_elementwise_max(a, b);
#else
    f2 r; r.x = fmaxf(a.x, b.x); r.y = fmaxf(a.y, b.y); return r;
#endif
}

// async 16B global->LDS (dest = wave-uniform base + lane*16)
__device__ __forceinline__ void gld16(const void* g, void* l) {
    __builtin_amdgcn_global_load_lds((const __attribute__((address_space(1))) void*)g,
                                     (__attribute__((address_space(3))) void*)l, 16, 0, 0);
}

// 16-lane DPP row reductions (VALU-only)
__device__ __forceinline__ float rowsum16(float x) {
    int t;
    t = __builtin_amdgcn_update_dpp(0, __float_as_int(x), 0x128, 0xF, 0xF, false); x += __int_as_float(t);
    t = __builtin_amdgcn_update_dpp(0, __float_as_int(x), 0x124, 0xF, 0xF, false); x += __int_as_float(t);
    t = __builtin_amdgcn_update_dpp(0, __float_as_int(x), 0x122, 0xF, 0xF, false); x += __int_as_float(t);
    t = __builtin_amdgcn_update_dpp(0, __float_as_int(x), 0x121, 0xF, 0xF, false); x += __int_as_float(t);
    return x;
}
__device__ __forceinline__ float rowmax16(float x) {
    int t;
    t = __builtin_amdgcn_update_dpp(0, __float_as_int(x), 0x128, 0xF, 0xF, false); x = fmaxf(x, __int_as_float(t));
    t = __builtin_amdgcn_update_dpp(0, __float_as_int(x), 0x124, 0xF, 0xF, false); x = fmaxf(x, __int_as_float(t));
    t = __builtin_amdgcn_update_dpp(0, __float_as_int(x), 0x122, 0xF, 0xF, false); x = fmaxf(x, __int_as_float(t));
    t = __builtin_amdgcn_update_dpp(0, __float_as_int(x), 0x121, 0xF, 0xF, false); x = fmaxf(x, __int_as_float(t));
    return x;
}

// ---------------- fused prep: x-cast + weight transposes (packed bt2) + zeroing + small vecs ----------------
#define XB 3750   // ceil(960000/256)
#define TB 1408   // ceil(360448/256)
#define ZB 240    // ceil((1024+2*NN+192)/256)

__global__ __launch_bounds__(256) void k_prep(const float* __restrict__ x, ushort* __restrict__ xc,
        const float* W0, const float* W1, const float* W2, const float* W3,
        const float* W4, const float* W5, const float* W6, const float* W7,
        ushort* bt0, ushort* bt1, ushort* bt2,
        int* __restrict__ zero_region,
        const float* b0, const float* a0, const float* b1, const float* a1,
        const float* b2, const float* a2, const float* g0, const float* be0,
        const float* g1, const float* be1, ushort* __restrict__ smallv) {
    int b = blockIdx.x, t = threadIdx.x;
    if (b < XB) {
        int i = b * 256 + t;
        if (i < NN * INP / 4) {
            float4 v = ((const float4*)x)[i];
            ushort4 o;
            o.x = bf16_of_float(v.x); o.y = bf16_of_float(v.y);
            o.z = bf16_of_float(v.z); o.w = bf16_of_float(v.w);
            ((ushort4*)xc)[i] = o;
        }
    } else if (b < XB + TB) {
        const float* Ws[8] = {W0, W1, W2, W3, W4, W5, W6, W7};
        int g = (b - XB) * 256 + t;               // < 360448
        if (g < 98304) {                          // bt0: 3 segs of [256 x 128]
            int seg = g >> 15, local = g & 32767;
            int n = local >> 7, k = local & 127;
            bt0[g] = bf16_of_float(Ws[seg][k * 256 + n]);
        } else if (g < 229376) {                  // bt1: 2 segs of [256 x 256]
            int gg = g - 98304;
            int seg = gg >> 16, local = gg & 65535;
            int n = local >> 8, k = local & 255;
            bt1[gg] = bf16_of_float(Ws[3 + seg][k * 256 + n]);
        } else if (g < 360448) {                  // bt2: packed [512 x 256], rows = 3x160 + 32 pad
            int gg = g - 229376;
            int n = gg >> 8, k = gg & 255;
            ushort val = 0;
            if (n < 480) {
                int seg = n / 160;
                int nn = n - seg * 160;
                val = bf16_of_float(Ws[5 + seg][k * 160 + nn]);
            }
            bt2[gg] = val;
        }
    } else if (b < XB + TB + ZB) {
        int i = (b - XB - TB) * 256 + t;
        if (i < 1024 + 2 * NN + 192) zero_region[i] = 0;   // bnstats+cnt+pos+binCnt+binPos+total
    } else {
        const float* ptrs[10] = {b0, a0, b1, a1, b2, a2, g0, be0, g1, be1};
        const int sz[10] = {256, 256, 256, 256, 160, 160, 256, 256, 256, 256};
        int off = 0;
        for (int j = 0; j < 10; j++) {
            if (t < sz[j]) smallv[off + t] = bf16_of_float(ptrs[j][t]);
            off += sz[j];
        }
    }
}

// ---------------- CSR build (range-assignment form) + parallel degree sort ----------------
// beg[v] is ANY disjoint range base with length cnt[v] -- no global prefix order needed.
// r12: CSR chain fused 5 -> 3 kernels (binhist+beg merged; order+scatter merged).

__global__ __launch_bounds__(256) void k_hist(const int* __restrict__ dst, int* __restrict__ cnt) {
    int e = blockIdx.x * 256 + threadIdx.x;
    if (e < EE) atomicAdd(&cnt[dst[e]], 1);
}

// fused: global 64-bin degree histogram + range assignment (both consume final cnt, independent outputs)
__global__ __launch_bounds__(256) void k_binbeg(const int* __restrict__ cnt, int* __restrict__ binCnt,
                                                int* __restrict__ beg, int* __restrict__ total) {
    __shared__ int lb[64];
    __shared__ int ss[256];
    __shared__ int base;
    int t = threadIdx.x;
    if (t < 64) lb[t] = 0;
    __syncthreads();
    int i = blockIdx.x * 256 + t;
    int c = (i < NN) ? cnt[i] : 0;
    if (i < NN) atomicAdd(&lb[63 - min(c, 63)], 1);   // bin 0 = highest degree
    ss[t] = c;
    __syncthreads();
    if (t < 64 && lb[t] > 0) atomicAdd(&binCnt[t], lb[t]);
    for (int o = 1; o < 256; o <<= 1) {
        int v = (t >= o) ? ss[t - o] : 0;
        __syncthreads();
        ss[t] += v;
        __syncthreads();
    }
    if (t == 255) base = atomicAdd(total, ss[255]);
    __syncthreads();
    if (i < NN) beg[i] = base + ss[t] - c;     // exclusive within-block + reserved base
}

// fused: node placement into order[] (blocks [0,NBLK)) + edge scatter (remaining blocks).
// The two halves are mutually independent; both depend only on k_binbeg's outputs.
__global__ __launch_bounds__(256) void k_orderscatter(const int* __restrict__ cnt, const int* __restrict__ binCnt,
                                                      int* __restrict__ binPos, int* __restrict__ order,
                                                      const int* __restrict__ src, const int* __restrict__ dst,
                                                      const int* __restrict__ beg, int* __restrict__ pos,
                                                      int* __restrict__ srcs) {
    int t = threadIdx.x;
    if (blockIdx.x < NBLK) {
        __shared__ int lb[64], lbase[64], bpre[64];
        if (t < 64) { lb[t] = 0; bpre[t] = binCnt[t]; }
        __syncthreads();
        int i = blockIdx.x * 256 + t;
        int bin = 0, rank = 0;
        if (i < NN) {
            bin = 63 - min(cnt[i], 63);
            rank = atomicAdd(&lb[bin], 1);
        }
        for (int o = 1; o < 64; o <<= 1) {         // in-LDS inclusive scan of binCnt
            int v = (t >= o && t < 64) ? bpre[t - o] : 0;
            __syncthreads();
            if (t < 64) bpre[t] += v;
            __syncthreads();
        }
        if (t < 64 && lb[t] > 0)
            lbase[t] = bpre[t] - binCnt[t] + atomicAdd(&binPos[t], lb[t]);   // exclusive base + reservation
        __syncthreads();
        if (i < NN) order[lbase[bin] + rank] = i;
    } else {
        int e = (blockIdx.x - NBLK) * 256 + t;
        if (e < EE) {
            int d = dst[e];
            int p = atomicAdd(&pos[d], 1);
            srcs[beg[d] + p] = src[e];
        }
    }
}

// ---------------- tiled bf16 MFMA GEMM ----------------
// 128x128 tile, 4 waves, BK=32. r13: T3 minimum 2-phase -- double-buffered LDS
// (2x16KB), next-tile gld16 issued BEFORE current tile's ds_read+MFMA, ONE
// barrier per K-step (vmcnt drain overlapped by compute) vs r12's two barriers
// with fully-exposed staging latency. Math/layout identical to r10.
// MFMA operands SWAPPED (bg, af): acc holds C^T fragment; lane&15 = output ROW,
// regs = 4 consecutive output COLS -> one ushort4 store per acc[i][c].

template<int K, int SEGW, int NSEG>
__global__ __launch_bounds__(256) void k_gemm_tiled(const ushort* __restrict__ A,
                                                    const ushort* __restrict__ Bt,
                                                    ushort* __restrict__ o0, ushort* __restrict__ o1,
                                                    ushort* __restrict__ o2) {
    __shared__ ushort As[2 * 128 * 32];   // per buffer: chunk c (16B) at byte c*16; row = c>>2, kpart = c&3
    __shared__ ushort Bs[2 * 128 * 32];
    int t = threadIdx.x;
    int wave = t >> 6, lane = t & 63;
    int m = lane & 15, q = lane >> 4;
    int row0 = blockIdx.x * 128, col0 = blockIdx.y * 128;
    int wr = (wave >> 1) << 6, wc = (wave & 1) << 6;
    f4v acc[4][4] = {};
    int c1 = t, c2 = t + 256;
    int ar1 = min(row0 + (c1 >> 2), NN - 1);
    int ar2 = min(row0 + (c2 >> 2), NN - 1);
    const ushort* a1 = A + (size_t)ar1 * K + (c1 & 3) * 8;
    const ushort* a2 = A + (size_t)ar2 * K + (c2 & 3) * 8;
    const ushort* b1 = Bt + (size_t)(col0 + (c1 >> 2)) * K + (c1 & 3) * 8;
    const ushort* b2 = Bt + (size_t)(col0 + (c2 >> 2)) * K + (c2 & 3) * 8;
    int wbase = wave << 10;               // bytes: 64 lanes x 16B per wave
    char* AsB = (char*)As;
    char* BsB = (char*)Bs;

    // prologue: stage tile kt=0 into buffer 0
    gld16(a1, AsB + wbase);
    gld16(a2, AsB + 4096 + wbase);
    gld16(b1, BsB + wbase);
    gld16(b2, BsB + 4096 + wbase);
    __syncthreads();                      // vmcnt(0) drain (compiler-emitted)

#pragma unroll
    for (int kt = 0; kt < K; kt += 32) {
        int cur = (kt >> 5) & 1;
        int curo = cur * 4096;            // ushort offset of current buffer
        if (kt + 32 < K) {                // issue next-tile loads BEFORE compute
            int nb = (cur ^ 1) * 8192;    // byte offset of other buffer
            gld16(a1 + kt + 32, AsB + nb + wbase);
            gld16(a2 + kt + 32, AsB + nb + 4096 + wbase);
            gld16(b1 + kt + 32, BsB + nb + wbase);
            gld16(b2 + kt + 32, BsB + nb + 4096 + wbase);
        }
        s8v af[4], bg[4];
#pragma unroll
        for (int i = 0; i < 4; i++) af[i] = *(const s8v*)&As[curo + (wr + i * 16 + m) * 32 + q * 8];
#pragma unroll
        for (int c = 0; c < 4; c++) bg[c] = *(const s8v*)&Bs[curo + (wc + c * 16 + m) * 32 + q * 8];
#pragma unroll
        for (int i = 0; i < 4; i++)
#pragma unroll
            for (int c = 0; c < 4; c++)   // SWAPPED operands: acc holds C^T fragment
                acc[i][c] = __builtin_amdgcn_mfma_f32_16x16x32_bf16(bg[c], af[i], acc[i][c], 0, 0, 0);
        if (kt + 32 < K) __syncthreads(); // one barrier per step; next-tile vmcnt drain covered by MFMA
    }

    // epilogue: value(lane,reg r) = C[row0+wr+i*16+m][col0+wc+c*16+q*4+r]
#pragma unroll
    for (int c = 0; c < 4; c++) {
        int gcb = col0 + wc + c * 16;             // 16-col tile: SEGW mult of 16 => single segment
        if (gcb < SEGW * NSEG) {
            int seg = gcb / SEGW;
            int colb = gcb - seg * SEGW + q * 4;  // + r (r=0..3 contiguous)
            ushort* op = seg == 0 ? o0 : (seg == 1 ? o1 : o2);
#pragma unroll
            for (int i = 0; i < 4; i++) {
                int gr = row0 + wr + i * 16 + m;
                if (gr < NN) {
                    ushort4 s4;
                    s4.x = bf16_of_float(acc[i][c][0]);
                    s4.y = bf16_of_float(acc[i][c][1]);
                    s4.z = bf16_of_float(acc[i][c][2]);
                    s4.w = bf16_of_float(acc[i][c][3]);
                    *(ushort4*)&op[(size_t)gr * SEGW + colb] = s4;
                }
            }
        }
    }
}

// ---------------- fused GATv2 edge phase (+ final log-softmax), degree-sorted ----------------
// One wave per dst node (taken from order[]), all 4 heads. lane=16h+j holds dims
// [4j..4j+3] of head h. All features bf16. attn pre-scaled by log2(e) -> exp2f.
// r12: quad loop software-pipelined. r13: all float2 math moved to native
// <2 x float> ext_vector so the backend forms VOP3P v_pk_{add,mul,fma,max}_f32
// (scalar-pair IR cannot) -- ~30% fewer VALU issue slots/edge, bit-identical.

template<int DH, bool FINAL>
__global__ __launch_bounds__(256) void k_aggregate(const ushort* __restrict__ fs, const ushort* __restrict__ fd,
                                                   const ushort* __restrict__ res,
                                                   const ushort* __restrict__ attn,
                                                   const ushort* __restrict__ bias,
                                                   const int* __restrict__ beg, const int* __restrict__ cnt,
                                                   const int* __restrict__ srcs,
                                                   const int* __restrict__ order,
                                                   ushort* __restrict__ outb, float* __restrict__ outf) {
    constexpr int F = HH * DH;
    constexpr int JMAX = DH >> 2;
    int tt = threadIdx.x;
    int v = __builtin_amdgcn_readfirstlane(order[blockIdx.x * 4 + (tt >> 6)]);
    int lane = tt & 63;
    int h = lane >> 4, j = lane & 15;
    bool act = j < JMAX;
    unsigned off = h * DH + 4 * j;
    unsigned vbase = (unsigned)v * F + off;
    f2 fda = {0.f, 0.f}, fdb = {0.f, 0.f}, ava = {0.f, 0.f}, avb = {0.f, 0.f};
    if (act) {
        uint2 d = *(const uint2*)&fd[vbase];
        fda = cvt2v(d.x); fdb = cvt2v(d.y);
        uint2 a = *(const uint2*)&attn[off];
        const float LOG2E = 1.4426950408889634f;
        ava = cvt2v(a.x) * LOG2E; avb = cvt2v(a.y) * LOG2E;
    }
    float l = 0.f;
    f2 acca = {0.f, 0.f}, accb = {0.f, 0.f};
    int b0i = beg[v], end = b0i + cnt[v];

    auto ldrow = [&](int u, f2& ra, f2& rb) {
        ra = splat2(0.f); rb = splat2(0.f);
        if (act) {
            uint2 d = *(const uint2*)&fs[(unsigned)u * F + off];
            ra = cvt2v(d.x); rb = cvt2v(d.y);
        }
    };
    auto dotlr = [&](const f2& ra, const f2& rb) -> float {
        f2 t0 = ra + fda;
        f2 t1 = rb + fdb;
        t0 = f2maxv(t0, t0 * 0.2f);            // leaky_relu slope 0.2 == max(t, 0.2t)
        t1 = f2maxv(t1, t1 * 0.2f);
        f2 p2 = ava * t0;
        p2 = f2fmav(avb, t1, p2);
        return p2.x + p2.y;                    // log2-domain score
    };
    auto quadc = [&](const f2& r0a, const f2& r0b, const f2& r1a, const f2& r1b,
                     const f2& r2a, const f2& r2b, const f2& r3a, const f2& r3b) {
        float p0 = rowsum16(dotlr(r0a, r0b));
        float p1 = rowsum16(dotlr(r1a, r1b));
        float p2 = rowsum16(dotlr(r2a, r2b));
        float p3 = rowsum16(dotlr(r3a, r3b));
        float w0 = exp2f(p0), w1 = exp2f(p1), w2 = exp2f(p2), w3 = exp2f(p3);
        l += (w0 + w1) + (w2 + w3);
        acca = f2fmav(splat2(w0), r0a, acca);
        accb = f2fmav(splat2(w0), r0b, accb);
        acca = f2fmav(splat2(w1), r1a, acca);
        accb = f2fmav(splat2(w1), r1b, accb);
        acca = f2fmav(splat2(w2), r2a, acca);
        accb = f2fmav(splat2(w2), r2b, accb);
        acca = f2fmav(splat2(w3), r3a, acca);
        accb = f2fmav(splat2(w3), r3b, accb);
    };

    int i = b0i;
    if (i + 3 < end) {
        // pipeline prologue: load quad 0
        int u0 = srcs[i], u1 = srcs[i+1], u2 = srcs[i+2], u3 = srcs[i+3];
        f2 r0a, r0b, r1a, r1b, r2a, r2b, r3a, r3b;
        ldrow(u0, r0a, r0b); ldrow(u1, r1a, r1b);
        ldrow(u2, r2a, r2b); ldrow(u3, r3a, r3b);
        for (i += 4; i + 3 < end; i += 4) {
            // issue next quad's loads BEFORE computing current quad (latency hides under VALU)
            int n0 = srcs[i], n1 = srcs[i+1], n2 = srcs[i+2], n3 = srcs[i+3];
            f2 s0a, s0b, s1a, s1b, s2a, s2b, s3a, s3b;
            ldrow(n0, s0a, s0b); ldrow(n1, s1a, s1b);
            ldrow(n2, s2a, s2b); ldrow(n3, s3a, s3b);
            quadc(r0a, r0b, r1a, r1b, r2a, r2b, r3a, r3b);
            r0a = s0a; r0b = s0b; r1a = s1a; r1b = s1b;
            r2a = s2a; r2b = s2b; r3a = s3a; r3b = s3b;
        }
        // drain: compute the last prefetched quad
        quadc(r0a, r0b, r1a, r1b, r2a, r2b, r3a, r3b);
    }
    for (; i < end; i++) {
        f2 ra, rb;
        ldrow(srcs[i], ra, rb);
        float p0 = rowsum16(dotlr(ra, rb));
        float w0 = exp2f(p0);
        l += w0;
        acca = f2fmav(splat2(w0), ra, acca);
        accb = f2fmav(splat2(w0), rb, accb);
    }

    float4 o4 = {0.f, 0.f, 0.f, 0.f};
    if (act) {
        float inv = 1.f / fmaxf(l, 1e-9f);
        uint2 rr = *(const uint2*)&res[vbase];
        f2 rl = cvt2v(rr.x), rh = cvt2v(rr.y);
        uint2 bb = *(const uint2*)&bias[off];
        f2 bl = cvt2v(bb.x), bh = cvt2v(bb.y);
        o4.x = acca.x * inv + rl.x + bl.x;
        o4.y = acca.y * inv + rl.y + bl.y;
        o4.z = accb.x * inv + rh.x + bh.x;
        o4.w = accb.y * inv + rh.y + bh.y;
        if (!FINAL) {
            o4.x = fmaxf(o4.x, 0.f); o4.y = fmaxf(o4.y, 0.f);
            o4.z = fmaxf(o4.z, 0.f); o4.w = fmaxf(o4.w, 0.f);
        }
    }
    if (!FINAL) {
        if (act) {
            ushort4 s4;
            s4.x = bf16_of_float(o4.x); s4.y = bf16_of_float(o4.y);
            s4.z = bf16_of_float(o4.z); s4.w = bf16_of_float(o4.w);
            *(ushort4*)&outb[vbase] = s4;
        }
    } else {
        // head mean: sum over the 4 head groups (lanes 16/32 apart, same j)
#pragma unroll
        for (int msk = 16; msk <= 32; msk <<= 1) {
            o4.x += __shfl_xor(o4.x, msk, 64);
            o4.y += __shfl_xor(o4.y, msk, 64);
            o4.z += __shfl_xor(o4.z, msk, 64);
            o4.w += __shfl_xor(o4.w, msk, 64);
        }
        float4 zv = make_float4(0.25f * o4.x, 0.25f * o4.y, 0.25f * o4.z, 0.25f * o4.w);
        float mx4 = act ? fmaxf(fmaxf(zv.x, zv.y), fmaxf(zv.z, zv.w)) : -1e30f;
        float mx = rowmax16(mx4);
        float es = 0.f;
        if (act) es = __expf(zv.x - mx) + __expf(zv.y - mx) + __expf(zv.z - mx) + __expf(zv.w - mx);
        float ssum = rowsum16(es);
        float lse = mx + logf(ssum);
        if (act && h == 0) {
            float4 w4 = make_float4(zv.x - lse, zv.y - lse, zv.z - lse, zv.w - lse);
            *(float4*)&outf[(size_t)v * CC + 4 * j] = w4;
        }
    }
}

// ---------------- batchnorm stats (bf16 in), r8-proven structure: 60k global atomics ----------------
// r12: dual accumulator chains + unroll-4 (8 row-loads in flight) -- this kernel
// runs at ~1 wave/SIMD (235 blocks), so ILP is the only latency cover available.

__global__ __launch_bounds__(256) void k_bn_partial(const ushort* __restrict__ h, float* __restrict__ sum,
                                                    float* __restrict__ sumsq) {
    int c = threadIdx.x;
    int r0 = blockIdx.x * 128;
    int r1 = min(NN, r0 + 128);
    float s0 = 0.f, ss0 = 0.f, s1 = 0.f, ss1 = 0.f;
    int r = r0;
#pragma unroll 4
    for (; r + 1 < r1; r += 2) {
        float v0 = b2f(h[(size_t)r * HD + c]);
        float v1 = b2f(h[(size_t)(r + 1) * HD + c]);
        s0 += v0; ss0 = __fmaf_rn(v0, v0, ss0);
        s1 += v1; ss1 = __fmaf_rn(v1, v1, ss1);
    }
    if (r < r1) {
        float v0 = b2f(h[(size_t)r * HD + c]);
        s0 += v0; ss0 = __fmaf_rn(v0, v0, ss0);
    }
    atomicAdd(&sum[c], s0 + s1);
    atomicAdd(&sumsq[c], ss0 + ss1);
}

// ---------------- batchnorm normalize (bf16 in, bf16 out), x4 vectorized ----------------

__global__ __launch_bounds__(256) void k_bn_norm(const ushort* __restrict__ hin, const float* __restrict__ sum,
                                                 const float* __restrict__ sumsq,
                                                 const ushort* __restrict__ g,
                                                 const ushort* __restrict__ be,
                                                 ushort* __restrict__ hbf) {
    int i4 = blockIdx.x * 256 + threadIdx.x;
    if (i4 < NN * HD / 4) {
        int base = i4 * 4;
        int c = base & (HD - 1);
        ushort4 hv = ((const ushort4*)hin)[i4];
        ushort4 ov;
        float vv[4] = {b2f(hv.x), b2f(hv.y), b2f(hv.z), b2f(hv.w)};
        ushort* po = (ushort*)&ov;
#pragma unroll
        for (int k = 0; k < 4; k++) {
            float mean = sum[c + k] * (1.0f / NN);
            float var = fmaxf(sumsq[c + k] * (1.0f / NN) - mean * mean, 0.f);
            float y = b2f(g[c + k]) * (vv[k] - mean) * rsqrtf(var + 1e-5f) + b2f(be[c + k]);
            po[k] = bf16_of_float(fmaxf(y, 0.f));
        }
        ((ushort4*)hbf)[i4] = ov;
    }
}

// ---------------- driver ----------------

static inline char* alignup(char* p) { return (char*)(((size_t)p + 255) & ~(size_t)255); }

extern "C" void kernel_launch(void* const* d_in, const int* in_sizes, int n_in,
                              void* d_out, int out_size, void* d_ws, size_t ws_size,
                              hipStream_t stream) {
    const float* x     = (const float*)d_in[0];
    const int*  src    = (const int*)d_in[1];
    const int*  dst    = (const int*)d_in[2];
    const float* Wsrc0 = (const float*)d_in[3];
    const float* Wdst0 = (const float*)d_in[4];
    const float* b0    = (const float*)d_in[5];
    const float* attn0 = (const float*)d_in[6];
    const float* resW0 = (const float*)d_in[7];
    const float* Wsrc1 = (const float*)d_in[8];
    const float* Wdst1 = (const float*)d_in[9];
    const float* b1    = (const float*)d_in[10];
    const float* attn1 = (const float*)d_in[11];
    const float* Wsrc2 = (const float*)d_in[12];
    const float* Wdst2 = (const float*)d_in[13];
    const float* b2    = (const float*)d_in[14];
    const float* attn2 = (const float*)d_in[15];
    const float* resW2 = (const float*)d_in[16];
    const float* g0    = (const float*)d_in[17];
    const float* be0   = (const float*)d_in[18];
    const float* g1    = (const float*)d_in[19];
    const float* be1   = (const float*)d_in[20];

    char* w = (char*)d_ws;
    const size_t NF = (size_t)NN * HD;
    ushort* fsb = (ushort*)w; w += NF * 2;
    ushort* fdb = (ushort*)w; w += NF * 2;
    ushort* resb= (ushort*)w; w += NF * 2;
    ushort* hag = (ushort*)w; w += NF * 2;
    ushort* hbf = (ushort*)w; w += NF * 2;
    ushort* xc  = (ushort*)w; w += (size_t)NN * INP * 2;
    ushort* bt0 = (ushort*)w; w += 768 * 128 * 2;   // 3 segs [256x128]
    ushort* bt1 = (ushort*)w; w += 512 * 256 * 2;   // 2 segs [256x256]
    ushort* bt2 = (ushort*)w; w += 512 * 256 * 2;   // packed 3x160 + 32 pad rows, K=256
    ushort* smallv = (ushort*)w; w += 2368 * 2; w = alignup(w);
    // zeroed in k_prep: bnstats[1024] + cnt[NN] + pos[NN] + binCnt[64] + binPos[64] + total[64]
    float* bnstats = (float*)w; w += 1024 * 4;
    int* cnt    = (int*)w; w += NN * 4;
    int* pos    = (int*)w; w += NN * 4;
    int* binCnt = (int*)w; w += 64 * 4;
    int* binPos = (int*)w; w += 64 * 4;
    int* total  = (int*)w; w += 64 * 4; w = alignup(w);
    int* beg    = (int*)w; w += NN * 4; w = alignup(w);
    int* order  = (int*)w; w += NN * 4; w = alignup(w);
    int* srcs   = (int*)w; w += EE * 4;

    const ushort* c_b0    = smallv + 0;
    const ushort* c_attn0 = smallv + 256;
    const ushort* c_b1    = smallv + 512;
    const ushort* c_attn1 = smallv + 768;
    const ushort* c_b2    = smallv + 1024;
    const ushort* c_attn2 = smallv + 1184;
    const ushort* c_g0    = smallv + 1344;
    const ushort* c_be0   = smallv + 1600;
    const ushort* c_g1    = smallv + 1856;
    const ushort* c_be1   = smallv + 2112;

    // 1: fused prep
    k_prep<<<XB + TB + ZB + 1, 256, 0, stream>>>(x, xc,
        Wsrc0, Wdst0, resW0, Wsrc1, Wdst1, Wsrc2, Wdst2, resW2, bt0, bt1, bt2,
        (int*)bnstats,
        b0, attn0, b1, attn1, b2, attn2, g0, be0, g1, be1, smallv);

    // 2-4: CSR range-assignment + parallel degree sort (fused: 3 launches)
    k_hist<<<(EE + 255) / 256, 256, 0, stream>>>(dst, cnt);
    k_binbeg<<<NBLK, 256, 0, stream>>>(cnt, binCnt, beg, total);
    k_orderscatter<<<NBLK + (EE + 255) / 256, 256, 0, stream>>>(cnt, binCnt, binPos, order,
                                                                src, dst, beg, pos, srcs);

    const int MB = (NN + 127) / 128;   // 235

    // 5-8: layer 0
    k_gemm_tiled<128, 256, 3><<<dim3(MB, 6), 256, 0, stream>>>(xc, bt0, fsb, fdb, resb);
    k_aggregate<DD, false><<<NN / 4, 256, 0, stream>>>(fsb, fdb, resb, c_attn0, c_b0,
        beg, cnt, srcs, order, hag, nullptr);
    k_bn_partial<<<MB, 256, 0, stream>>>(hag, bnstats, bnstats + 256);
    k_bn_norm<<<(int)((NF / 4 + 255) / 256), 256, 0, stream>>>(hag, bnstats, bnstats + 256,
                                                               c_g0, c_be0, hbf);

    // 9-12: layer 1 (identity residual = hbf)
    k_gemm_tiled<256, 256, 2><<<dim3(MB, 4), 256, 0, stream>>>(hbf, bt1, fsb, fdb, nullptr);
    k_aggregate<DD, false><<<NN / 4, 256, 0, stream>>>(fsb, fdb, hbf, c_attn1, c_b1,
        beg, cnt, srcs, order, hag, nullptr);
    k_bn_partial<<<MB, 256, 0, stream>>>(hag, bnstats + 512, bnstats + 768);
    k_bn_norm<<<(int)((NF / 4 + 255) / 256), 256, 0, stream>>>(hag, bnstats + 512, bnstats + 768,
                                                               c_g1, c_be1, hbf);

    // 13-14: layer 2 (packed 160-col segments) + fused head-mean/log_softmax -> d_out
    k_gemm_tiled<256, 160, 3><<<dim3(MB, 4), 256, 0, stream>>>(hbf, bt2, fsb, fdb, resb);
    k_aggregate<CC, true><<<NN / 4, 256, 0, stream>>>(fsb, fdb, resb, c_attn2, c_b2,
        beg, cnt, srcs, order, nullptr, (float*)d_out);
}

// Round 3
// 361.192 us; speedup vs baseline: 1.0007x; 1.0007x over previous
//
#include <hip/hip_runtime.h>
#include <hip/hip_bf16.h>
#include <math.h>

#define NN 30000
#define EE 400000
#define INP 128
#define HH 4
#define DD 64
#define CC 40
#define HD 256   // H*D
#define HC 160   // H*C
#define NBLK 118 // ceil(NN/256)

typedef unsigned short ushort;
typedef __attribute__((ext_vector_type(8))) short s8v;   // 8 x bf16 bits (4 VGPRs)
typedef __attribute__((ext_vector_type(4))) float f4v;   // MFMA accumulator
typedef __attribute__((ext_vector_type(2))) float f2;    // packed f32 pair -> v_pk_*_f32

// Inputs: fp32 storage holding bf16-rounded values (established r1-r4).

__device__ inline ushort bf16_of_float(float f) {
    __hip_bfloat16 b = __float2bfloat16(f);
    return *(ushort*)&b;
}
__device__ __forceinline__ float b2f(ushort u) { return __uint_as_float(((unsigned)u) << 16); }

// dword holding 2 packed bf16 -> native <2 x float> (low half, high half)
__device__ __forceinline__ f2 cvt2v(unsigned d) {
    f2 r;
    r.x = __uint_as_float(d << 16);
    r.y = __uint_as_float(d & 0xFFFF0000u);
    return r;
}
__device__ __forceinline__ f2 splat2(float s) { f2 r = {s, s}; return r; }
__device__ __forceinline__ f2 f2fmav(f2 a, f2 b, f2 c) {
#if __has_builtin(__builtin_elementwise_fma)
    return __builtin_elementwise_fma(a, b, c);
#else
    f2 r; r.x = __fmaf_rn(a.x, b.x, c.x); r.y = __fmaf_rn(a.y, b.y, c.y); return r;
#endif
}
__device__ __forceinline__ f2 f2maxv(f2 a, f2 b) {
#if __has_builtin(__builtin_elementwise_max)
    return __builtin_elementwise_max(a, b);
#else
    f2 r; r.x = fmaxf(a.x, b.x); r.y = fmaxf(a.y, b.y); return r;
#endif
}

// async 16B global->LDS (dest = wave-uniform base + lane*16)
__device__ __forceinline__ void gld16(const void* g, void* l) {
    __builtin_amdgcn_global_load_lds((const __attribute__((address_space(1))) void*)g,
                                     (__attribute__((address_space(3))) void*)l, 16, 0, 0);
}

// 16-lane DPP row reductions (VALU-only)
__device__ __forceinline__ float rowsum16(float x) {
    int t;
    t = __builtin_amdgcn_update_dpp(0, __float_as_int(x), 0x128, 0xF, 0xF, false); x += __int_as_float(t);
    t = __builtin_amdgcn_update_dpp(0, __float_as_int(x), 0x124, 0xF, 0xF, false); x += __int_as_float(t);
    t = __builtin_amdgcn_update_dpp(0, __float_as_int(x), 0x122, 0xF, 0xF, false); x += __int_as_float(t);
    t = __builtin_amdgcn_update_dpp(0, __float_as_int(x), 0x121, 0xF, 0xF, false); x += __int_as_float(t);
    return x;
}
__device__ __forceinline__ float rowmax16(float x) {
    int t;
    t = __builtin_amdgcn_update_dpp(0, __float_as_int(x), 0x128, 0xF, 0xF, false); x = fmaxf(x, __int_as_float(t));
    t = __builtin_amdgcn_update_dpp(0, __float_as_int(x), 0x124, 0xF, 0xF, false); x = fmaxf(x, __int_as_float(t));
    t = __builtin_amdgcn_update_dpp(0, __float_as_int(x), 0x122, 0xF, 0xF, false); x = fmaxf(x, __int_as_float(t));
    t = __builtin_amdgcn_update_dpp(0, __float_as_int(x), 0x121, 0xF, 0xF, false); x = fmaxf(x, __int_as_float(t));
    return x;
}

// ---------------- fused prep: x-cast + weight transposes (packed bt2) + zeroing + small vecs ----------------
#define XB 3750   // ceil(960000/256)
#define TB 1408   // ceil(360448/256)
#define ZB 240    // ceil((1024+2*NN+192)/256)

__global__ __launch_bounds__(256) void k_prep(const float* __restrict__ x, ushort* __restrict__ xc,
        const float* W0, const float* W1, const float* W2, const float* W3,
        const float* W4, const float* W5, const float* W6, const float* W7,
        ushort* bt0, ushort* bt1, ushort* bt2,
        int* __restrict__ zero_region,
        const float* b0, const float* a0, const float* b1, const float* a1,
        const float* b2, const float* a2, const float* g0, const float* be0,
        const float* g1, const float* be1, ushort* __restrict__ smallv) {
    int b = blockIdx.x, t = threadIdx.x;
    if (b < XB) {
        int i = b * 256 + t;
        if (i < NN * INP / 4) {
            float4 v = ((const float4*)x)[i];
            ushort4 o;
            o.x = bf16_of_float(v.x); o.y = bf16_of_float(v.y);
            o.z = bf16_of_float(v.z); o.w = bf16_of_float(v.w);
            ((ushort4*)xc)[i] = o;
        }
    } else if (b < XB + TB) {
        const float* Ws[8] = {W0, W1, W2, W3, W4, W5, W6, W7};
        int g = (b - XB) * 256 + t;               // < 360448
        if (g < 98304) {                          // bt0: 3 segs of [256 x 128]
            int seg = g >> 15, local = g & 32767;
            int n = local >> 7, k = local & 127;
            bt0[g] = bf16_of_float(Ws[seg][k * 256 + n]);
        } else if (g < 229376) {                  // bt1: 2 segs of [256 x 256]
            int gg = g - 98304;
            int seg = gg >> 16, local = gg & 65535;
            int n = local >> 8, k = local & 255;
            bt1[gg] = bf16_of_float(Ws[3 + seg][k * 256 + n]);
        } else if (g < 360448) {                  // bt2: packed [512 x 256], rows = 3x160 + 32 pad
            int gg = g - 229376;
            int n = gg >> 8, k = gg & 255;
            ushort val = 0;
            if (n < 480) {
                int seg = n / 160;
                int nn = n - seg * 160;
                val = bf16_of_float(Ws[5 + seg][k * 160 + nn]);
            }
            bt2[gg] = val;
        }
    } else if (b < XB + TB + ZB) {
        int i = (b - XB - TB) * 256 + t;
        if (i < 1024 + 2 * NN + 192) zero_region[i] = 0;   // bnstats+cnt+pos+binCnt+binPos+total
    } else {
        const float* ptrs[10] = {b0, a0, b1, a1, b2, a2, g0, be0, g1, be1};
        const int sz[10] = {256, 256, 256, 256, 160, 160, 256, 256, 256, 256};
        int off = 0;
        for (int j = 0; j < 10; j++) {
            if (t < sz[j]) smallv[off + t] = bf16_of_float(ptrs[j][t]);
            off += sz[j];
        }
    }
}

// ---------------- CSR build (range-assignment form) + parallel degree sort ----------------
// beg[v] is ANY disjoint range base with length cnt[v] -- no global prefix order needed.
// r14: ranges padded to multiples of 4 (scan over rcnt) so every beg[v] is
// 16B-aligned -> aggregate loads srcs quads as one int4.

__global__ __launch_bounds__(256) void k_hist(const int* __restrict__ dst, int* __restrict__ cnt) {
    int e = blockIdx.x * 256 + threadIdx.x;
    if (e < EE) atomicAdd(&cnt[dst[e]], 1);
}

// fused: global 64-bin degree histogram + range assignment (both consume final cnt, independent outputs)
__global__ __launch_bounds__(256) void k_binbeg(const int* __restrict__ cnt, int* __restrict__ binCnt,
                                                int* __restrict__ beg, int* __restrict__ total) {
    __shared__ int lb[64];
    __shared__ int ss[256];
    __shared__ int base;
    int t = threadIdx.x;
    if (t < 64) lb[t] = 0;
    __syncthreads();
    int i = blockIdx.x * 256 + t;
    int c = (i < NN) ? cnt[i] : 0;
    int rc = (c + 3) & ~3;                            // 4-padded range length
    if (i < NN) atomicAdd(&lb[63 - min(c, 63)], 1);   // bin 0 = highest degree
    ss[t] = rc;
    __syncthreads();
    if (t < 64 && lb[t] > 0) atomicAdd(&binCnt[t], lb[t]);
    for (int o = 1; o < 256; o <<= 1) {
        int v = (t >= o) ? ss[t - o] : 0;
        __syncthreads();
        ss[t] += v;
        __syncthreads();
    }
    if (t == 255) base = atomicAdd(total, ss[255]);   // block sums are multiples of 4 -> base 4-aligned
    __syncthreads();
    if (i < NN) beg[i] = base + ss[t] - rc;           // exclusive within-block + reserved base (4-aligned)
}

// fused: node placement into order[] (blocks [0,NBLK)) + edge scatter (remaining blocks).
// The two halves are mutually independent; both depend only on k_binbeg's outputs.
__global__ __launch_bounds__(256) void k_orderscatter(const int* __restrict__ cnt, const int* __restrict__ binCnt,
                                                      int* __restrict__ binPos, int* __restrict__ order,
                                                      const int* __restrict__ src, const int* __restrict__ dst,
                                                      const int* __restrict__ beg, int* __restrict__ pos,
                                                      int* __restrict__ srcs) {
    int t = threadIdx.x;
    if (blockIdx.x < NBLK) {
        __shared__ int lb[64], lbase[64], bpre[64];
        if (t < 64) { lb[t] = 0; bpre[t] = binCnt[t]; }
        __syncthreads();
        int i = blockIdx.x * 256 + t;
        int bin = 0, rank = 0;
        if (i < NN) {
            bin = 63 - min(cnt[i], 63);
            rank = atomicAdd(&lb[bin], 1);
        }
        for (int o = 1; o < 64; o <<= 1) {         // in-LDS inclusive scan of binCnt
            int v = (t >= o && t < 64) ? bpre[t - o] : 0;
            __syncthreads();
            if (t < 64) bpre[t] += v;
            __syncthreads();
        }
        if (t < 64 && lb[t] > 0)
            lbase[t] = bpre[t] - binCnt[t] + atomicAdd(&binPos[t], lb[t]);   // exclusive base + reservation
        __syncthreads();
        if (i < NN) order[lbase[bin] + rank] = i;
    } else {
        int e = (blockIdx.x - NBLK) * 256 + t;
        if (e < EE) {
            int d = dst[e];
            int p = atomicAdd(&pos[d], 1);
            srcs[beg[d] + p] = src[e];
        }
    }
}

// ---------------- tiled bf16 MFMA GEMM, single-buffer staging (r10-proven; r14 reverted
// from r13's double-buffer -- 32KB LDS halved blocks/CU for no measured gain) ----------------
// 128x128 tile, 4 waves, BK=32. MFMA operands SWAPPED (bg, af): acc holds the
// transposed fragment -- lane&15 = output ROW, regs = 4 consecutive output COLS
// -> each acc[i][c] packs to one ushort4 store (16 stores/lane vs 64).

template<int K, int SEGW, int NSEG>
__global__ __launch_bounds__(256) void k_gemm_tiled(const ushort* __restrict__ A,
                                                    const ushort* __restrict__ Bt,
                                                    ushort* __restrict__ o0, ushort* __restrict__ o1,
                                                    ushort* __restrict__ o2) {
    __shared__ ushort As[128 * 32];   // chunk c (16B) at byte c*16; row = c>>2, kpart = c&3
    __shared__ ushort Bs[128 * 32];
    int t = threadIdx.x;
    int wave = t >> 6, lane = t & 63;
    int m = lane & 15, q = lane >> 4;
    int row0 = blockIdx.x * 128, col0 = blockIdx.y * 128;
    int wr = (wave >> 1) << 6, wc = (wave & 1) << 6;
    f4v acc[4][4] = {};
    int c1 = t, c2 = t + 256;
    int ar1 = min(row0 + (c1 >> 2), NN - 1);
    int ar2 = min(row0 + (c2 >> 2), NN - 1);
    const ushort* a1 = A + (size_t)ar1 * K + (c1 & 3) * 8;
    const ushort* a2 = A + (size_t)ar2 * K + (c2 & 3) * 8;
    const ushort* b1 = Bt + (size_t)(col0 + (c1 >> 2)) * K + (c1 & 3) * 8;
    const ushort* b2 = Bt + (size_t)(col0 + (c2 >> 2)) * K + (c2 & 3) * 8;
    int wbase = wave << 10;
    char* AsB = (char*)As;
    char* BsB = (char*)Bs;

#pragma unroll
    for (int kt = 0; kt < K; kt += 32) {
        __syncthreads();
        gld16(a1 + kt, AsB + wbase);
        gld16(a2 + kt, AsB + 4096 + wbase);
        gld16(b1 + kt, BsB + wbase);
        gld16(b2 + kt, BsB + 4096 + wbase);
        __syncthreads();
        s8v af[4], bg[4];
#pragma unroll
        for (int i = 0; i < 4; i++) af[i] = *(const s8v*)&As[(wr + i * 16 + m) * 32 + q * 8];
#pragma unroll
        for (int c = 0; c < 4; c++) bg[c] = *(const s8v*)&Bs[(wc + c * 16 + m) * 32 + q * 8];
#pragma unroll
        for (int i = 0; i < 4; i++)
#pragma unroll
            for (int c = 0; c < 4; c++)   // SWAPPED operands: acc holds C^T fragment
                acc[i][c] = __builtin_amdgcn_mfma_f32_16x16x32_bf16(bg[c], af[i], acc[i][c], 0, 0, 0);
    }

    // epilogue: value(lane,reg r) = C[row0+wr+i*16+m][col0+wc+c*16+q*4+r]
#pragma unroll
    for (int c = 0; c < 4; c++) {
        int gcb = col0 + wc + c * 16;             // 16-col tile: SEGW mult of 16 => single segment
        if (gcb < SEGW * NSEG) {
            int seg = gcb / SEGW;
            int colb = gcb - seg * SEGW + q * 4;  // + r (r=0..3 contiguous)
            ushort* op = seg == 0 ? o0 : (seg == 1 ? o1 : o2);
#pragma unroll
            for (int i = 0; i < 4; i++) {
                int gr = row0 + wr + i * 16 + m;
                if (gr < NN) {
                    ushort4 s4;
                    s4.x = bf16_of_float(acc[i][c][0]);
                    s4.y = bf16_of_float(acc[i][c][1]);
                    s4.z = bf16_of_float(acc[i][c][2]);
                    s4.w = bf16_of_float(acc[i][c][3]);
                    *(ushort4*)&op[(size_t)gr * SEGW + colb] = s4;
                }
            }
        }
    }
}

// ---------------- fused GATv2 edge phase (+ final log-softmax), degree-sorted ----------------
// One wave per dst node (taken from order[]), all 4 heads. lane=16h+j holds dims
// [4j..4j+3] of head h. All features bf16. attn pre-scaled by log2(e) -> exp2f.
// r14: r2's VGPR_Count=32 proved the compiler SANK the r12 prefetch back to its
// use (8 live rows can't fit 32 VGPRs) -> every quad serially exposed
// idx-load + row-gather latency. Fix: (a) srcs quad = one aligned int4 (ranges
// 4-padded), (b) idx carried one quad AHEAD so row-issue never waits on an
// index load, (c) sched_barrier(0) after the prefetch-issue cluster pins the
// loads above quadc. Arithmetic order unchanged (bit-exact vs r12/r13).

template<int DH, bool FINAL>
__global__ __launch_bounds__(256) void k_aggregate(const ushort* __restrict__ fs, const ushort* __restrict__ fd,
                                                   const ushort* __restrict__ res,
                                                   const ushort* __restrict__ attn,
                                                   const ushort* __restrict__ bias,
                                                   const int* __restrict__ beg, const int* __restrict__ cnt,
                                                   const int* __restrict__ srcs,
                                                   const int* __restrict__ order,
                                                   ushort* __restrict__ outb, float* __restrict__ outf) {
    constexpr int F = HH * DH;
    constexpr int JMAX = DH >> 2;
    int tt = threadIdx.x;
    int v = __builtin_amdgcn_readfirstlane(order[blockIdx.x * 4 + (tt >> 6)]);
    int lane = tt & 63;
    int h = lane >> 4, j = lane & 15;
    bool act = j < JMAX;
    unsigned off = h * DH + 4 * j;
    unsigned vbase = (unsigned)v * F + off;
    f2 fda = {0.f, 0.f}, fdb = {0.f, 0.f}, ava = {0.f, 0.f}, avb = {0.f, 0.f};
    if (act) {
        uint2 d = *(const uint2*)&fd[vbase];
        fda = cvt2v(d.x); fdb = cvt2v(d.y);
        uint2 a = *(const uint2*)&attn[off];
        const float LOG2E = 1.4426950408889634f;
        ava = cvt2v(a.x) * LOG2E; avb = cvt2v(a.y) * LOG2E;
    }
    float l = 0.f;
    f2 acca = {0.f, 0.f}, accb = {0.f, 0.f};
    int b0i = beg[v], end = b0i + cnt[v];

    auto ldrow = [&](int u, f2& ra, f2& rb) {
        ra = splat2(0.f); rb = splat2(0.f);
        if (act) {
            uint2 d = *(const uint2*)&fs[(unsigned)u * F + off];
            ra = cvt2v(d.x); rb = cvt2v(d.y);
        }
    };
    auto dotlr = [&](const f2& ra, const f2& rb) -> float {
        f2 t0 = ra + fda;
        f2 t1 = rb + fdb;
        t0 = f2maxv(t0, t0 * 0.2f);            // leaky_relu slope 0.2 == max(t, 0.2t)
        t1 = f2maxv(t1, t1 * 0.2f);
        f2 p2 = ava * t0;
        p2 = f2fmav(avb, t1, p2);
        return p2.x + p2.y;                    // log2-domain score
    };
    auto quadc = [&](const f2& r0a, const f2& r0b, const f2& r1a, const f2& r1b,
                     const f2& r2a, const f2& r2b, const f2& r3a, const f2& r3b) {
        float p0 = rowsum16(dotlr(r0a, r0b));
        float p1 = rowsum16(dotlr(r1a, r1b));
        float p2 = rowsum16(dotlr(r2a, r2b));
        float p3 = rowsum16(dotlr(r3a, r3b));
        float w0 = exp2f(p0), w1 = exp2f(p1), w2 = exp2f(p2), w3 = exp2f(p3);
        l += (w0 + w1) + (w2 + w3);
        acca = f2fmav(splat2(w0), r0a, acca);
        accb = f2fmav(splat2(w0), r0b, accb);
        acca = f2fmav(splat2(w1), r1a, acca);
        accb = f2fmav(splat2(w1), r1b, accb);
        acca = f2fmav(splat2(w2), r2a, acca);
        accb = f2fmav(splat2(w2), r2b, accb);
        acca = f2fmav(splat2(w3), r3a, acca);
        accb = f2fmav(splat2(w3), r3b, accb);
    };

    int i = b0i;
    if (i + 3 < end) {
        // pipeline prologue: idx quad0 (aligned int4) + its rows; idx quad1 issued early
        int4 u = *(const int4*)&srcs[i];
        f2 r0a, r0b, r1a, r1b, r2a, r2b, r3a, r3b;
        ldrow(u.x, r0a, r0b); ldrow(u.y, r1a, r1b);
        ldrow(u.z, r2a, r2b); ldrow(u.w, r3a, r3b);
        int4 un = (i + 7 < end) ? *(const int4*)&srcs[i + 4] : u;
        for (i += 4; i + 3 < end; i += 4) {
            // issue next quad's rows (idx already resident) + idx for quad n+2,
            // then pin them above the compute so the compiler can't sink them.
            f2 s0a, s0b, s1a, s1b, s2a, s2b, s3a, s3b;
            ldrow(un.x, s0a, s0b); ldrow(un.y, s1a, s1b);
            ldrow(un.z, s2a, s2b); ldrow(un.w, s3a, s3b);
            if (i + 7 < end) un = *(const int4*)&srcs[i + 4];
            __builtin_amdgcn_sched_barrier(0);
            quadc(r0a, r0b, r1a, r1b, r2a, r2b, r3a, r3b);
            // rotation copies are the s_waitcnt point for the s-loads (post-compute)
            r0a = s0a; r0b = s0b; r1a = s1a; r1b = s1b;
            r2a = s2a; r2b = s2b; r3a = s3a; r3b = s3b;
        }
        // drain: compute the last prefetched quad
        quadc(r0a, r0b, r1a, r1b, r2a, r2b, r3a, r3b);
    }
    for (; i < end; i++) {
        f2 ra, rb;
        ldrow(srcs[i], ra, rb);
        float p0 = rowsum16(dotlr(ra, rb));
        float w0 = exp2f(p0);
        l += w0;
        acca = f2fmav(splat2(w0), ra, acca);
        accb = f2fmav(splat2(w0), rb, accb);
    }

    float4 o4 = {0.f, 0.f, 0.f, 0.f};
    if (act) {
        float inv = 1.f / fmaxf(l, 1e-9f);
        uint2 rr = *(const uint2*)&res[vbase];
        f2 rl = cvt2v(rr.x), rh = cvt2v(rr.y);
        uint2 bb = *(const uint2*)&bias[off];
        f2 bl = cvt2v(bb.x), bh = cvt2v(bb.y);
        o4.x = acca.x * inv + rl.x + bl.x;
        o4.y = acca.y * inv + rl.y + bl.y;
        o4.z = accb.x * inv + rh.x + bh.x;
        o4.w = accb.y * inv + rh.y + bh.y;
        if (!FINAL) {
            o4.x = fmaxf(o4.x, 0.f); o4.y = fmaxf(o4.y, 0.f);
            o4.z = fmaxf(o4.z, 0.f); o4.w = fmaxf(o4.w, 0.f);
        }
    }
    if (!FINAL) {
        if (act) {
            ushort4 s4;
            s4.x = bf16_of_float(o4.x); s4.y = bf16_of_float(o4.y);
            s4.z = bf16_of_float(o4.z); s4.w = bf16_of_float(o4.w);
            *(ushort4*)&outb[vbase] = s4;
        }
    } else {
        // head mean: sum over the 4 head groups (lanes 16/32 apart, same j)
#pragma unroll
        for (int msk = 16; msk <= 32; msk <<= 1) {
            o4.x += __shfl_xor(o4.x, msk, 64);
            o4.y += __shfl_xor(o4.y, msk, 64);
            o4.z += __shfl_xor(o4.z, msk, 64);
            o4.w += __shfl_xor(o4.w, msk, 64);
        }
        float4 zv = make_float4(0.25f * o4.x, 0.25f * o4.y, 0.25f * o4.z, 0.25f * o4.w);
        float mx4 = act ? fmaxf(fmaxf(zv.x, zv.y), fmaxf(zv.z, zv.w)) : -1e30f;
        float mx = rowmax16(mx4);
        float es = 0.f;
        if (act) es = __expf(zv.x - mx) + __expf(zv.y - mx) + __expf(zv.z - mx) + __expf(zv.w - mx);
        float ssum = rowsum16(es);
        float lse = mx + logf(ssum);
        if (act && h == 0) {
            float4 w4 = make_float4(zv.x - lse, zv.y - lse, zv.z - lse, zv.w - lse);
            *(float4*)&outf[(size_t)v * CC + 4 * j] = w4;
        }
    }
}

// ---------------- batchnorm stats (bf16 in), r8-proven structure: 60k global atomics ----------------
// r12: dual accumulator chains + unroll-4 (8 row-loads in flight) -- this kernel
// runs at ~1 wave/SIMD (235 blocks), so ILP is the only latency cover available.

__global__ __launch_bounds__(256) void k_bn_partial(const ushort* __restrict__ h, float* __restrict__ sum,
                                                    float* __restrict__ sumsq) {
    int c = threadIdx.x;
    int r0 = blockIdx.x * 128;
    int r1 = min(NN, r0 + 128);
    float s0 = 0.f, ss0 = 0.f, s1 = 0.f, ss1 = 0.f;
    int r = r0;
#pragma unroll 4
    for (; r + 1 < r1; r += 2) {
        float v0 = b2f(h[(size_t)r * HD + c]);
        float v1 = b2f(h[(size_t)(r + 1) * HD + c]);
        s0 += v0; ss0 = __fmaf_rn(v0, v0, ss0);
        s1 += v1; ss1 = __fmaf_rn(v1, v1, ss1);
    }
    if (r < r1) {
        float v0 = b2f(h[(size_t)r * HD + c]);
        s0 += v0; ss0 = __fmaf_rn(v0, v0, ss0);
    }
    atomicAdd(&sum[c], s0 + s1);
    atomicAdd(&sumsq[c], ss0 + ss1);
}

// ---------------- batchnorm normalize (bf16 in, bf16 out), x4 vectorized ----------------

__global__ __launch_bounds__(256) void k_bn_norm(const ushort* __restrict__ hin, const float* __restrict__ sum,
                                                 const float* __restrict__ sumsq,
                                                 const ushort* __restrict__ g,
                                                 const ushort* __restrict__ be,
                                                 ushort* __restrict__ hbf) {
    int i4 = blockIdx.x * 256 + threadIdx.x;
    if (i4 < NN * HD / 4) {
        int base = i4 * 4;
        int c = base & (HD - 1);
        ushort4 hv = ((const ushort4*)hin)[i4];
        ushort4 ov;
        float vv[4] = {b2f(hv.x), b2f(hv.y), b2f(hv.z), b2f(hv.w)};
        ushort* po = (ushort*)&ov;
#pragma unroll
        for (int k = 0; k < 4; k++) {
            float mean = sum[c + k] * (1.0f / NN);
            float var = fmaxf(sumsq[c + k] * (1.0f / NN) - mean * mean, 0.f);
            float y = b2f(g[c + k]) * (vv[k] - mean) * rsqrtf(var + 1e-5f) + b2f(be[c + k]);
            po[k] = bf16_of_float(fmaxf(y, 0.f));
        }
        ((ushort4*)hbf)[i4] = ov;
    }
}

// ---------------- driver ----------------

static inline char* alignup(char* p) { return (char*)(((size_t)p + 255) & ~(size_t)255); }

extern "C" void kernel_launch(void* const* d_in, const int* in_sizes, int n_in,
                              void* d_out, int out_size, void* d_ws, size_t ws_size,
                              hipStream_t stream) {
    const float* x     = (const float*)d_in[0];
    const int*  src    = (const int*)d_in[1];
    const int*  dst    = (const int*)d_in[2];
    const float* Wsrc0 = (const float*)d_in[3];
    const float* Wdst0 = (const float*)d_in[4];
    const float* b0    = (const float*)d_in[5];
    const float* attn0 = (const float*)d_in[6];
    const float* resW0 = (const float*)d_in[7];
    const float* Wsrc1 = (const float*)d_in[8];
    const float* Wdst1 = (const float*)d_in[9];
    const float* b1    = (const float*)d_in[10];
    const float* attn1 = (const float*)d_in[11];
    const float* Wsrc2 = (const float*)d_in[12];
    const float* Wdst2 = (const float*)d_in[13];
    const float* b2    = (const float*)d_in[14];
    const float* attn2 = (const float*)d_in[15];
    const float* resW2 = (const float*)d_in[16];
    const float* g0    = (const float*)d_in[17];
    const float* be0   = (const float*)d_in[18];
    const float* g1    = (const float*)d_in[19];
    const float* be1   = (const float*)d_in[20];

    char* w = (char*)d_ws;
    const size_t NF = (size_t)NN * HD;
    ushort* fsb = (ushort*)w; w += NF * 2;
    ushort* fdb = (ushort*)w; w += NF * 2;
    ushort* resb= (ushort*)w; w += NF * 2;
    ushort* hag = (ushort*)w; w += NF * 2;
    ushort* hbf = (ushort*)w; w += NF * 2;
    ushort* xc  = (ushort*)w; w += (size_t)NN * INP * 2;
    ushort* bt0 = (ushort*)w; w += 768 * 128 * 2;   // 3 segs [256x128]
    ushort* bt1 = (ushort*)w; w += 512 * 256 * 2;   // 2 segs [256x256]
    ushort* bt2 = (ushort*)w; w += 512 * 256 * 2;   // packed 3x160 + 32 pad rows, K=256
    ushort* smallv = (ushort*)w; w += 2368 * 2; w = alignup(w);
    // zeroed in k_prep: bnstats[1024] + cnt[NN] + pos[NN] + binCnt[64] + binPos[64] + total[64]
    float* bnstats = (float*)w; w += 1024 * 4;
    int* cnt    = (int*)w; w += NN * 4;
    int* pos    = (int*)w; w += NN * 4;
    int* binCnt = (int*)w; w += 64 * 4;
    int* binPos = (int*)w; w += 64 * 4;
    int* total  = (int*)w; w += 64 * 4; w = alignup(w);
    int* beg    = (int*)w; w += NN * 4; w = alignup(w);
    int* order  = (int*)w; w += NN * 4; w = alignup(w);
    int* srcs   = (int*)w; w += (size_t)(EE + 3 * NN + 64) * 4;   // 4-padded ranges

    const ushort* c_b0    = smallv + 0;
    const ushort* c_attn0 = smallv + 256;
    const ushort* c_b1    = smallv + 512;
    const ushort* c_attn1 = smallv + 768;
    const ushort* c_b2    = smallv + 1024;
    const ushort* c_attn2 = smallv + 1184;
    const ushort* c_g0    = smallv + 1344;
    const ushort* c_be0   = smallv + 1600;
    const ushort* c_g1    = smallv + 1856;
    const ushort* c_be1   = smallv + 2112;

    // 1: fused prep
    k_prep<<<XB + TB + ZB + 1, 256, 0, stream>>>(x, xc,
        Wsrc0, Wdst0, resW0, Wsrc1, Wdst1, Wsrc2, Wdst2, resW2, bt0, bt1, bt2,
        (int*)bnstats,
        b0, attn0, b1, attn1, b2, attn2, g0, be0, g1, be1, smallv);

    // 2-4: CSR range-assignment + parallel degree sort (fused: 3 launches)
    k_hist<<<(EE + 255) / 256, 256, 0, stream>>>(dst, cnt);
    k_binbeg<<<NBLK, 256, 0, stream>>>(cnt, binCnt, beg, total);
    k_orderscatter<<<NBLK + (EE + 255) / 256, 256, 0, stream>>>(cnt, binCnt, binPos, order,
                                                                src, dst, beg, pos, srcs);

    const int MB = (NN + 127) / 128;   // 235

    // 5-8: layer 0
    k_gemm_tiled<128, 256, 3><<<dim3(MB, 6), 256, 0, stream>>>(xc, bt0, fsb, fdb, resb);
    k_aggregate<DD, false><<<NN / 4, 256, 0, stream>>>(fsb, fdb, resb, c_attn0, c_b0,
        beg, cnt, srcs, order, hag, nullptr);
    k_bn_partial<<<MB, 256, 0, stream>>>(hag, bnstats, bnstats + 256);
    k_bn_norm<<<(int)((NF / 4 + 255) / 256), 256, 0, stream>>>(hag, bnstats, bnstats + 256,
                                                               c_g0, c_be0, hbf);

    // 9-12: layer 1 (identity residual = hbf)
    k_gemm_tiled<256, 256, 2><<<dim3(MB, 4), 256, 0, stream>>>(hbf, bt1, fsb, fdb, nullptr);
    k_aggregate<DD, false><<<NN / 4, 256, 0, stream>>>(fsb, fdb, hbf, c_attn1, c_b1,
        beg, cnt, srcs, order, hag, nullptr);
    k_bn_partial<<<MB, 256, 0, stream>>>(hag, bnstats + 512, bnstats + 768);
    k_bn_norm<<<(int)((NF / 4 + 255) / 256), 256, 0, stream>>>(hag, bnstats + 512, bnstats + 768,
                                                               c_g1, c_be1, hbf);

    // 13-14: layer 2 (packed 160-col segments) + fused head-mean/log_softmax -> d_out
    k_gemm_tiled<256, 160, 3><<<dim3(MB, 4), 256, 0, stream>>>(hbf, bt2, fsb, fdb, resb);
    k_aggregate<CC, true><<<NN / 4, 256, 0, stream>>>(fsb, fdb, resb, c_attn2, c_b2,
        beg, cnt, srcs, order, nullptr, (float*)d_out);
}

// Round 4
// 354.283 us; speedup vs baseline: 1.0202x; 1.0195x over previous
//
#include <hip/hip_runtime.h>
#include <hip/hip_bf16.h>
#include <math.h>

#define NN 30000
#define EE 400000
#define INP 128
#define HH 4
#define DD 64
#define CC 40
#define HD 256   // H*D
#define HC 160   // H*C
#define NBLK 118 // ceil(NN/256)

typedef unsigned short ushort;
typedef __attribute__((ext_vector_type(8))) short s8v;   // 8 x bf16 bits (4 VGPRs)
typedef __attribute__((ext_vector_type(4))) float f4v;   // MFMA accumulator
typedef __attribute__((ext_vector_type(2))) float f2;    // f32 pair in a VGPR pair

// Inputs: fp32 storage holding bf16-rounded values (established r1-r4).

__device__ inline ushort bf16_of_float(float f) {
    __hip_bfloat16 b = __float2bfloat16(f);
    return *(ushort*)&b;
}
__device__ __forceinline__ float b2f(ushort u) { return __uint_as_float(((unsigned)u) << 16); }

// dword holding 2 packed bf16 -> native <2 x float> (low half, high half)
__device__ __forceinline__ f2 cvt2v(unsigned d) {
    f2 r;
    r.x = __uint_as_float(d << 16);
    r.y = __uint_as_float(d & 0xFFFF0000u);
    return r;
}
__device__ __forceinline__ f2 splat2(float s) { f2 r = {s, s}; return r; }

// r15: FORCED VOP3P packed-f32 ops. The backend scalarizes <2 x float> IR
// (r13 was a no-op at ISA level); these asm helpers are 1 instruction for 2
// IEEE-exact f32 ops. Operands are 64b VGPR pairs ("v" on v2f32).
__device__ __forceinline__ f2 pk_add(f2 a, f2 b) {
    f2 d; asm("v_pk_add_f32 %0, %1, %2" : "=v"(d) : "v"(a), "v"(b)); return d;
}
__device__ __forceinline__ f2 pk_mul(f2 a, f2 b) {
    f2 d; asm("v_pk_mul_f32 %0, %1, %2" : "=v"(d) : "v"(a), "v"(b)); return d;
}
__device__ __forceinline__ f2 pk_fma(f2 a, f2 b, f2 c) {
    f2 d; asm("v_pk_fma_f32 %0, %1, %2, %3" : "=v"(d) : "v"(a), "v"(b), "v"(c)); return d;
}
__device__ __forceinline__ f2 f2maxv(f2 a, f2 b) {
#if __has_builtin(__builtin_elementwise_max)
    return __builtin_elementwise_max(a, b);
#else
    f2 r; r.x = fmaxf(a.x, b.x); r.y = fmaxf(a.y, b.y); return r;
#endif
}

// async 16B global->LDS (dest = wave-uniform base + lane*16)
__device__ __forceinline__ void gld16(const void* g, void* l) {
    __builtin_amdgcn_global_load_lds((const __attribute__((address_space(1))) void*)g,
                                     (__attribute__((address_space(3))) void*)l, 16, 0, 0);
}

// 16-lane DPP row reductions (VALU-only)
__device__ __forceinline__ float rowsum16(float x) {
    int t;
    t = __builtin_amdgcn_update_dpp(0, __float_as_int(x), 0x128, 0xF, 0xF, false); x += __int_as_float(t);
    t = __builtin_amdgcn_update_dpp(0, __float_as_int(x), 0x124, 0xF, 0xF, false); x += __int_as_float(t);
    t = __builtin_amdgcn_update_dpp(0, __float_as_int(x), 0x122, 0xF, 0xF, false); x += __int_as_float(t);
    t = __builtin_amdgcn_update_dpp(0, __float_as_int(x), 0x121, 0xF, 0xF, false); x += __int_as_float(t);
    return x;
}
__device__ __forceinline__ float rowmax16(float x) {
    int t;
    t = __builtin_amdgcn_update_dpp(0, __float_as_int(x), 0x128, 0xF, 0xF, false); x = fmaxf(x, __int_as_float(t));
    t = __builtin_amdgcn_update_dpp(0, __float_as_int(x), 0x124, 0xF, 0xF, false); x = fmaxf(x, __int_as_float(t));
    t = __builtin_amdgcn_update_dpp(0, __float_as_int(x), 0x122, 0xF, 0xF, false); x = fmaxf(x, __int_as_float(t));
    t = __builtin_amdgcn_update_dpp(0, __float_as_int(x), 0x121, 0xF, 0xF, false); x = fmaxf(x, __int_as_float(t));
    return x;
}

// ---------------- fused prep: x-cast + weight transposes (packed bt2) + zeroing + small vecs ----------------
#define XB 3750   // ceil(960000/256)
#define TB 1408   // ceil(360448/256)
#define ZB 240    // ceil((1024+2*NN+192)/256)

__global__ __launch_bounds__(256) void k_prep(const float* __restrict__ x, ushort* __restrict__ xc,
        const float* W0, const float* W1, const float* W2, const float* W3,
        const float* W4, const float* W5, const float* W6, const float* W7,
        ushort* bt0, ushort* bt1, ushort* bt2,
        int* __restrict__ zero_region,
        const float* b0, const float* a0, const float* b1, const float* a1,
        const float* b2, const float* a2, const float* g0, const float* be0,
        const float* g1, const float* be1, ushort* __restrict__ smallv) {
    int b = blockIdx.x, t = threadIdx.x;
    if (b < XB) {
        int i = b * 256 + t;
        if (i < NN * INP / 4) {
            float4 v = ((const float4*)x)[i];
            ushort4 o;
            o.x = bf16_of_float(v.x); o.y = bf16_of_float(v.y);
            o.z = bf16_of_float(v.z); o.w = bf16_of_float(v.w);
            ((ushort4*)xc)[i] = o;
        }
    } else if (b < XB + TB) {
        const float* Ws[8] = {W0, W1, W2, W3, W4, W5, W6, W7};
        int g = (b - XB) * 256 + t;               // < 360448
        if (g < 98304) {                          // bt0: 3 segs of [256 x 128]
            int seg = g >> 15, local = g & 32767;
            int n = local >> 7, k = local & 127;
            bt0[g] = bf16_of_float(Ws[seg][k * 256 + n]);
        } else if (g < 229376) {                  // bt1: 2 segs of [256 x 256]
            int gg = g - 98304;
            int seg = gg >> 16, local = gg & 65535;
            int n = local >> 8, k = local & 255;
            bt1[gg] = bf16_of_float(Ws[3 + seg][k * 256 + n]);
        } else if (g < 360448) {                  // bt2: packed [512 x 256], rows = 3x160 + 32 pad
            int gg = g - 229376;
            int n = gg >> 8, k = gg & 255;
            ushort val = 0;
            if (n < 480) {
                int seg = n / 160;
                int nn = n - seg * 160;
                val = bf16_of_float(Ws[5 + seg][k * 160 + nn]);
            }
            bt2[gg] = val;
        }
    } else if (b < XB + TB + ZB) {
        int i = (b - XB - TB) * 256 + t;
        if (i < 1024 + 2 * NN + 192) zero_region[i] = 0;   // bnstats+cnt+pos+binCnt+binPos+total
    } else {
        const float* ptrs[10] = {b0, a0, b1, a1, b2, a2, g0, be0, g1, be1};
        const int sz[10] = {256, 256, 256, 256, 160, 160, 256, 256, 256, 256};
        int off = 0;
        for (int j = 0; j < 10; j++) {
            if (t < sz[j]) smallv[off + t] = bf16_of_float(ptrs[j][t]);
            off += sz[j];
        }
    }
}

// ---------------- CSR build (range-assignment form) + parallel degree sort ----------------
// beg[v] is ANY disjoint range base with length cnt[v] -- no global prefix order needed.
// r14: ranges padded to multiples of 4 (scan over rcnt) so every beg[v] is
// 16B-aligned -> aggregate loads srcs quads as one int4.

__global__ __launch_bounds__(256) void k_hist(const int* __restrict__ dst, int* __restrict__ cnt) {
    int e = blockIdx.x * 256 + threadIdx.x;
    if (e < EE) atomicAdd(&cnt[dst[e]], 1);
}

// fused: global 64-bin degree histogram + range assignment (both consume final cnt, independent outputs)
__global__ __launch_bounds__(256) void k_binbeg(const int* __restrict__ cnt, int* __restrict__ binCnt,
                                                int* __restrict__ beg, int* __restrict__ total) {
    __shared__ int lb[64];
    __shared__ int ss[256];
    __shared__ int base;
    int t = threadIdx.x;
    if (t < 64) lb[t] = 0;
    __syncthreads();
    int i = blockIdx.x * 256 + t;
    int c = (i < NN) ? cnt[i] : 0;
    int rc = (c + 3) & ~3;                            // 4-padded range length
    if (i < NN) atomicAdd(&lb[63 - min(c, 63)], 1);   // bin 0 = highest degree
    ss[t] = rc;
    __syncthreads();
    if (t < 64 && lb[t] > 0) atomicAdd(&binCnt[t], lb[t]);
    for (int o = 1; o < 256; o <<= 1) {
        int v = (t >= o) ? ss[t - o] : 0;
        __syncthreads();
        ss[t] += v;
        __syncthreads();
    }
    if (t == 255) base = atomicAdd(total, ss[255]);   // block sums are multiples of 4 -> base 4-aligned
    __syncthreads();
    if (i < NN) beg[i] = base + ss[t] - rc;           // exclusive within-block + reserved base (4-aligned)
}

// fused: node placement into order[] (blocks [0,NBLK)) + edge scatter (remaining blocks).
// The two halves are mutually independent; both depend only on k_binbeg's outputs.
__global__ __launch_bounds__(256) void k_orderscatter(const int* __restrict__ cnt, const int* __restrict__ binCnt,
                                                      int* __restrict__ binPos, int* __restrict__ order,
                                                      const int* __restrict__ src, const int* __restrict__ dst,
                                                      const int* __restrict__ beg, int* __restrict__ pos,
                                                      int* __restrict__ srcs) {
    int t = threadIdx.x;
    if (blockIdx.x < NBLK) {
        __shared__ int lb[64], lbase[64], bpre[64];
        if (t < 64) { lb[t] = 0; bpre[t] = binCnt[t]; }
        __syncthreads();
        int i = blockIdx.x * 256 + t;
        int bin = 0, rank = 0;
        if (i < NN) {
            bin = 63 - min(cnt[i], 63);
            rank = atomicAdd(&lb[bin], 1);
        }
        for (int o = 1; o < 64; o <<= 1) {         // in-LDS inclusive scan of binCnt
            int v = (t >= o && t < 64) ? bpre[t - o] : 0;
            __syncthreads();
            if (t < 64) bpre[t] += v;
            __syncthreads();
        }
        if (t < 64 && lb[t] > 0)
            lbase[t] = bpre[t] - binCnt[t] + atomicAdd(&binPos[t], lb[t]);   // exclusive base + reservation
        __syncthreads();
        if (i < NN) order[lbase[bin] + rank] = i;
    } else {
        int e = (blockIdx.x - NBLK) * 256 + t;
        if (e < EE) {
            int d = dst[e];
            int p = atomicAdd(&pos[d], 1);
            srcs[beg[d] + p] = src[e];
        }
    }
}

// ---------------- tiled bf16 MFMA GEMM, single-buffer staging (r10-proven) ----------------
// 128x128 tile, 4 waves, BK=32. MFMA operands SWAPPED (bg, af): acc holds the
// transposed fragment. r15: XCD-chunked bijective block swizzle (m204 form),
// col-tile-fastest within each XCD chunk -- the 4-6 blocks sharing an A
// row-panel land on ONE XCD's L2 instead of re-fetching from LLC per XCD.

template<int K, int SEGW, int NSEG>
__global__ __launch_bounds__(256) void k_gemm_tiled(const ushort* __restrict__ A,
                                                    const ushort* __restrict__ Bt,
                                                    ushort* __restrict__ o0, ushort* __restrict__ o1,
                                                    ushort* __restrict__ o2) {
    __shared__ ushort As[128 * 32];   // chunk c (16B) at byte c*16; row = c>>2, kpart = c&3
    __shared__ ushort Bs[128 * 32];
    int t = threadIdx.x;
    int wave = t >> 6, lane = t & 63;
    int m = lane & 15, q = lane >> 4;

    // XCD swizzle: dispatch id ld -> (rowTile, colTile), col fastest per chunk
    int nwg = gridDim.x * gridDim.y;
    int NB = gridDim.y;
    int ld = blockIdx.x + gridDim.x * blockIdx.y;
    int xcd = ld & 7, pos = ld >> 3;
    int qq = nwg >> 3, rr = nwg & 7;
    int base = (xcd < rr) ? xcd * (qq + 1) : rr * (qq + 1) + (xcd - rr) * qq;
    int swz = base + pos;
    int row0 = (swz / NB) * 128, col0 = (swz % NB) * 128;

    int wr = (wave >> 1) << 6, wc = (wave & 1) << 6;
    f4v acc[4][4] = {};
    int c1 = t, c2 = t + 256;
    int ar1 = min(row0 + (c1 >> 2), NN - 1);
    int ar2 = min(row0 + (c2 >> 2), NN - 1);
    const ushort* a1 = A + (size_t)ar1 * K + (c1 & 3) * 8;
    const ushort* a2 = A + (size_t)ar2 * K + (c2 & 3) * 8;
    const ushort* b1 = Bt + (size_t)(col0 + (c1 >> 2)) * K + (c1 & 3) * 8;
    const ushort* b2 = Bt + (size_t)(col0 + (c2 >> 2)) * K + (c2 & 3) * 8;
    int wbase = wave << 10;
    char* AsB = (char*)As;
    char* BsB = (char*)Bs;

#pragma unroll
    for (int kt = 0; kt < K; kt += 32) {
        __syncthreads();
        gld16(a1 + kt, AsB + wbase);
        gld16(a2 + kt, AsB + 4096 + wbase);
        gld16(b1 + kt, BsB + wbase);
        gld16(b2 + kt, BsB + 4096 + wbase);
        __syncthreads();
        s8v af[4], bg[4];
#pragma unroll
        for (int i = 0; i < 4; i++) af[i] = *(const s8v*)&As[(wr + i * 16 + m) * 32 + q * 8];
#pragma unroll
        for (int c = 0; c < 4; c++) bg[c] = *(const s8v*)&Bs[(wc + c * 16 + m) * 32 + q * 8];
#pragma unroll
        for (int i = 0; i < 4; i++)
#pragma unroll
            for (int c = 0; c < 4; c++)   // SWAPPED operands: acc holds C^T fragment
                acc[i][c] = __builtin_amdgcn_mfma_f32_16x16x32_bf16(bg[c], af[i], acc[i][c], 0, 0, 0);
    }

    // epilogue: value(lane,reg r) = C[row0+wr+i*16+m][col0+wc+c*16+q*4+r]
#pragma unroll
    for (int c = 0; c < 4; c++) {
        int gcb = col0 + wc + c * 16;             // 16-col tile: SEGW mult of 16 => single segment
        if (gcb < SEGW * NSEG) {
            int seg = gcb / SEGW;
            int colb = gcb - seg * SEGW + q * 4;  // + r (r=0..3 contiguous)
            ushort* op = seg == 0 ? o0 : (seg == 1 ? o1 : o2);
#pragma unroll
            for (int i = 0; i < 4; i++) {
                int gr = row0 + wr + i * 16 + m;
                if (gr < NN) {
                    ushort4 s4;
                    s4.x = bf16_of_float(acc[i][c][0]);
                    s4.y = bf16_of_float(acc[i][c][1]);
                    s4.z = bf16_of_float(acc[i][c][2]);
                    s4.w = bf16_of_float(acc[i][c][3]);
                    *(ushort4*)&op[(size_t)gr * SEGW + colb] = s4;
                }
            }
        }
    }
}

// ---------------- fused GATv2 edge phase (+ final log-softmax), degree-sorted ----------------
// One wave per dst node (from order[]), all 4 heads; lane=16h+j holds dims
// [4j..4j+3] of head h. attn pre-scaled by log2(e) -> exp2.
// r15: (1) forced v_pk_*_f32 asm (backend scalarizes <2 x float> IR -- r13 was
// a no-op); (2) __builtin_amdgcn_exp2f (drops ocml wrapper; differs only for
// x<-126 where weight ~ 0); (3) ping-pong 2-deep unrolled pipeline with two
// NAMED register sets and idx carried a quad ahead -- no rotation copies for
// regalloc to coalesce away (r2-r3: VGPR=32 proved the prefetch kept dying).
// Accumulation order unchanged (bit-exact).

template<int DH, bool FINAL>
__global__ __launch_bounds__(256) void k_aggregate(const ushort* __restrict__ fs, const ushort* __restrict__ fd,
                                                   const ushort* __restrict__ res,
                                                   const ushort* __restrict__ attn,
                                                   const ushort* __restrict__ bias,
                                                   const int* __restrict__ beg, const int* __restrict__ cnt,
                                                   const int* __restrict__ srcs,
                                                   const int* __restrict__ order,
                                                   ushort* __restrict__ outb, float* __restrict__ outf) {
    constexpr int F = HH * DH;
    constexpr int JMAX = DH >> 2;
    int tt = threadIdx.x;
    int v = __builtin_amdgcn_readfirstlane(order[blockIdx.x * 4 + (tt >> 6)]);
    int lane = tt & 63;
    int h = lane >> 4, j = lane & 15;
    bool act = j < JMAX;
    unsigned off = h * DH + 4 * j;
    unsigned vbase = (unsigned)v * F + off;
    f2 fda = {0.f, 0.f}, fdb = {0.f, 0.f}, ava = {0.f, 0.f}, avb = {0.f, 0.f};
    if (act) {
        uint2 d = *(const uint2*)&fd[vbase];
        fda = cvt2v(d.x); fdb = cvt2v(d.y);
        uint2 a = *(const uint2*)&attn[off];
        const float LOG2E = 1.4426950408889634f;
        ava = cvt2v(a.x) * LOG2E; avb = cvt2v(a.y) * LOG2E;
    }
    const f2 c02 = {0.2f, 0.2f};
    float l = 0.f;
    f2 acca = {0.f, 0.f}, accb = {0.f, 0.f};
    int b0i = beg[v], end = b0i + cnt[v];

    struct Q8 { f2 a0, b0, a1, b1, a2, b2, a3, b3; };

    auto ldrow = [&](int u, f2& ra, f2& rb) {
        ra = splat2(0.f); rb = splat2(0.f);
        if (act) {
            uint2 d = *(const uint2*)&fs[(unsigned)u * F + off];
            ra = cvt2v(d.x); rb = cvt2v(d.y);
        }
    };
    auto ldq = [&](int4 u, Q8& r) {
        ldrow(u.x, r.a0, r.b0); ldrow(u.y, r.a1, r.b1);
        ldrow(u.z, r.a2, r.b2); ldrow(u.w, r.a3, r.b3);
    };
    auto dotlr = [&](const f2& ra, const f2& rb) -> float {
        f2 t0 = pk_add(ra, fda);
        f2 t1 = pk_add(rb, fdb);
        t0 = f2maxv(t0, pk_mul(t0, c02));      // leaky_relu slope 0.2 == max(t, 0.2t)
        t1 = f2maxv(t1, pk_mul(t1, c02));
        f2 p = pk_mul(ava, t0);
        p = pk_fma(avb, t1, p);
        return p.x + p.y;                      // log2-domain score
    };
    auto quadc = [&](const Q8& r) {
        float p0 = rowsum16(dotlr(r.a0, r.b0));
        float p1 = rowsum16(dotlr(r.a1, r.b1));
        float p2 = rowsum16(dotlr(r.a2, r.b2));
        float p3 = rowsum16(dotlr(r.a3, r.b3));
        float w0 = __builtin_amdgcn_exp2f(p0), w1 = __builtin_amdgcn_exp2f(p1);
        float w2 = __builtin_amdgcn_exp2f(p2), w3 = __builtin_amdgcn_exp2f(p3);
        l += (w0 + w1) + (w2 + w3);
        f2 s0 = splat2(w0), s1 = splat2(w1), s2 = splat2(w2), s3 = splat2(w3);
        acca = pk_fma(s0, r.a0, acca); accb = pk_fma(s0, r.b0, accb);
        acca = pk_fma(s1, r.a1, acca); accb = pk_fma(s1, r.b1, accb);
        acca = pk_fma(s2, r.a2, acca); accb = pk_fma(s2, r.b2, accb);
        acca = pk_fma(s3, r.a3, acca); accb = pk_fma(s3, r.b3, accb);
    };

    int i = b0i;
    int nfull = (end - b0i) >> 2;
    if (nfull > 0) {
        Q8 A, B;
        int4 u = *(const int4*)&srcs[i];            // idx quad 0
        ldq(u, A);                                  // rows quad 0
        int4 un = (nfull > 1) ? *(const int4*)&srcs[i + 4] : u;   // idx quad 1
        int q = 1;
        // invariant at head: quads [0, q-1) computed, A = rows[q-1], un = idx[q] (if q<nfull)
        for (; q + 1 < nfull; q += 2) {
            ldq(un, B);                                          // rows quad q
            un = *(const int4*)&srcs[i + (q + 1) * 4];           // idx quad q+1
            __builtin_amdgcn_sched_barrier(0);
            quadc(A);                                            // compute quad q-1
            ldq(un, A);                                          // rows quad q+1
            if (q + 2 < nfull) un = *(const int4*)&srcs[i + (q + 2) * 4];
            __builtin_amdgcn_sched_barrier(0);
            quadc(B);                                            // compute quad q
        }
        if (q < nfull) {       // one trailing quad, idx already in un
            ldq(un, B);
            __builtin_amdgcn_sched_barrier(0);
            quadc(A);
            quadc(B);
        } else {
            quadc(A);
        }
        i += nfull * 4;
    }
    for (; i < end; i++) {
        f2 ra, rb;
        ldrow(srcs[i], ra, rb);
        float p0 = rowsum16(dotlr(ra, rb));
        float w0 = __builtin_amdgcn_exp2f(p0);
        l += w0;
        f2 s0 = splat2(w0);
        acca = pk_fma(s0, ra, acca);
        accb = pk_fma(s0, rb, accb);
    }

    float4 o4 = {0.f, 0.f, 0.f, 0.f};
    if (act) {
        float inv = 1.f / fmaxf(l, 1e-9f);
        uint2 rr = *(const uint2*)&res[vbase];
        f2 rl = cvt2v(rr.x), rh = cvt2v(rr.y);
        uint2 bb = *(const uint2*)&bias[off];
        f2 bl = cvt2v(bb.x), bh = cvt2v(bb.y);
        o4.x = acca.x * inv + rl.x + bl.x;
        o4.y = acca.y * inv + rl.y + bl.y;
        o4.z = accb.x * inv + rh.x + bh.x;
        o4.w = accb.y * inv + rh.y + bh.y;
        if (!FINAL) {
            o4.x = fmaxf(o4.x, 0.f); o4.y = fmaxf(o4.y, 0.f);
            o4.z = fmaxf(o4.z, 0.f); o4.w = fmaxf(o4.w, 0.f);
        }
    }
    if (!FINAL) {
        if (act) {
            ushort4 s4;
            s4.x = bf16_of_float(o4.x); s4.y = bf16_of_float(o4.y);
            s4.z = bf16_of_float(o4.z); s4.w = bf16_of_float(o4.w);
            *(ushort4*)&outb[vbase] = s4;
        }
    } else {
        // head mean: sum over the 4 head groups (lanes 16/32 apart, same j)
#pragma unroll
        for (int msk = 16; msk <= 32; msk <<= 1) {
            o4.x += __shfl_xor(o4.x, msk, 64);
            o4.y += __shfl_xor(o4.y, msk, 64);
            o4.z += __shfl_xor(o4.z, msk, 64);
            o4.w += __shfl_xor(o4.w, msk, 64);
        }
        float4 zv = make_float4(0.25f * o4.x, 0.25f * o4.y, 0.25f * o4.z, 0.25f * o4.w);
        float mx4 = act ? fmaxf(fmaxf(zv.x, zv.y), fmaxf(zv.z, zv.w)) : -1e30f;
        float mx = rowmax16(mx4);
        float es = 0.f;
        if (act) es = __expf(zv.x - mx) + __expf(zv.y - mx) + __expf(zv.z - mx) + __expf(zv.w - mx);
        float ssum = rowsum16(es);
        float lse = mx + logf(ssum);
        if (act && h == 0) {
            float4 w4 = make_float4(zv.x - lse, zv.y - lse, zv.z - lse, zv.w - lse);
            *(float4*)&outf[(size_t)v * CC + 4 * j] = w4;
        }
    }
}

// ---------------- batchnorm stats (bf16 in), r8-proven structure: 60k global atomics ----------------
// r12: dual accumulator chains + unroll-4 (8 row-loads in flight) -- this kernel
// runs at ~1 wave/SIMD (235 blocks), so ILP is the only latency cover available.

__global__ __launch_bounds__(256) void k_bn_partial(const ushort* __restrict__ h, float* __restrict__ sum,
                                                    float* __restrict__ sumsq) {
    int c = threadIdx.x;
    int r0 = blockIdx.x * 128;
    int r1 = min(NN, r0 + 128);
    float s0 = 0.f, ss0 = 0.f, s1 = 0.f, ss1 = 0.f;
    int r = r0;
#pragma unroll 4
    for (; r + 1 < r1; r += 2) {
        float v0 = b2f(h[(size_t)r * HD + c]);
        float v1 = b2f(h[(size_t)(r + 1) * HD + c]);
        s0 += v0; ss0 = __fmaf_rn(v0, v0, ss0);
        s1 += v1; ss1 = __fmaf_rn(v1, v1, ss1);
    }
    if (r < r1) {
        float v0 = b2f(h[(size_t)r * HD + c]);
        s0 += v0; ss0 = __fmaf_rn(v0, v0, ss0);
    }
    atomicAdd(&sum[c], s0 + s1);
    atomicAdd(&sumsq[c], ss0 + ss1);
}

// ---------------- batchnorm normalize (bf16 in, bf16 out), x4 vectorized ----------------

__global__ __launch_bounds__(256) void k_bn_norm(const ushort* __restrict__ hin, const float* __restrict__ sum,
                                                 const float* __restrict__ sumsq,
                                                 const ushort* __restrict__ g,
                                                 const ushort* __restrict__ be,
                                                 ushort* __restrict__ hbf) {
    int i4 = blockIdx.x * 256 + threadIdx.x;
    if (i4 < NN * HD / 4) {
        int base = i4 * 4;
        int c = base & (HD - 1);
        ushort4 hv = ((const ushort4*)hin)[i4];
        ushort4 ov;
        float vv[4] = {b2f(hv.x), b2f(hv.y), b2f(hv.z), b2f(hv.w)};
        ushort* po = (ushort*)&ov;
#pragma unroll
        for (int k = 0; k < 4; k++) {
            float mean = sum[c + k] * (1.0f / NN);
            float var = fmaxf(sumsq[c + k] * (1.0f / NN) - mean * mean, 0.f);
            float y = b2f(g[c + k]) * (vv[k] - mean) * rsqrtf(var + 1e-5f) + b2f(be[c + k]);
            po[k] = bf16_of_float(fmaxf(y, 0.f));
        }
        ((ushort4*)hbf)[i4] = ov;
    }
}

// ---------------- driver ----------------

static inline char* alignup(char* p) { return (char*)(((size_t)p + 255) & ~(size_t)255); }

extern "C" void kernel_launch(void* const* d_in, const int* in_sizes, int n_in,
                              void* d_out, int out_size, void* d_ws, size_t ws_size,
                              hipStream_t stream) {
    const float* x     = (const float*)d_in[0];
    const int*  src    = (const int*)d_in[1];
    const int*  dst    = (const int*)d_in[2];
    const float* Wsrc0 = (const float*)d_in[3];
    const float* Wdst0 = (const float*)d_in[4];
    const float* b0    = (const float*)d_in[5];
    const float* attn0 = (const float*)d_in[6];
    const float* resW0 = (const float*)d_in[7];
    const float* Wsrc1 = (const float*)d_in[8];
    const float* Wdst1 = (const float*)d_in[9];
    const float* b1    = (const float*)d_in[10];
    const float* attn1 = (const float*)d_in[11];
    const float* Wsrc2 = (const float*)d_in[12];
    const float* Wdst2 = (const float*)d_in[13];
    const float* b2    = (const float*)d_in[14];
    const float* attn2 = (const float*)d_in[15];
    const float* resW2 = (const float*)d_in[16];
    const float* g0    = (const float*)d_in[17];
    const float* be0   = (const float*)d_in[18];
    const float* g1    = (const float*)d_in[19];
    const float* be1   = (const float*)d_in[20];

    char* w = (char*)d_ws;
    const size_t NF = (size_t)NN * HD;
    ushort* fsb = (ushort*)w; w += NF * 2;
    ushort* fdb = (ushort*)w; w += NF * 2;
    ushort* resb= (ushort*)w; w += NF * 2;
    ushort* hag = (ushort*)w; w += NF * 2;
    ushort* hbf = (ushort*)w; w += NF * 2;
    ushort* xc  = (ushort*)w; w += (size_t)NN * INP * 2;
    ushort* bt0 = (ushort*)w; w += 768 * 128 * 2;   // 3 segs [256x128]
    ushort* bt1 = (ushort*)w; w += 512 * 256 * 2;   // 2 segs [256x256]
    ushort* bt2 = (ushort*)w; w += 512 * 256 * 2;   // packed 3x160 + 32 pad rows, K=256
    ushort* smallv = (ushort*)w; w += 2368 * 2; w = alignup(w);
    // zeroed in k_prep: bnstats[1024] + cnt[NN] + pos[NN] + binCnt[64] + binPos[64] + total[64]
    float* bnstats = (float*)w; w += 1024 * 4;
    int* cnt    = (int*)w; w += NN * 4;
    int* pos    = (int*)w; w += NN * 4;
    int* binCnt = (int*)w; w += 64 * 4;
    int* binPos = (int*)w; w += 64 * 4;
    int* total  = (int*)w; w += 64 * 4; w = alignup(w);
    int* beg    = (int*)w; w += NN * 4; w = alignup(w);
    int* order  = (int*)w; w += NN * 4; w = alignup(w);
    int* srcs   = (int*)w; w += (size_t)(EE + 3 * NN + 64) * 4;   // 4-padded ranges

    const ushort* c_b0    = smallv + 0;
    const ushort* c_attn0 = smallv + 256;
    const ushort* c_b1    = smallv + 512;
    const ushort* c_attn1 = smallv + 768;
    const ushort* c_b2    = smallv + 1024;
    const ushort* c_attn2 = smallv + 1184;
    const ushort* c_g0    = smallv + 1344;
    const ushort* c_be0   = smallv + 1600;
    const ushort* c_g1    = smallv + 1856;
    const ushort* c_be1   = smallv + 2112;

    // 1: fused prep
    k_prep<<<XB + TB + ZB + 1, 256, 0, stream>>>(x, xc,
        Wsrc0, Wdst0, resW0, Wsrc1, Wdst1, Wsrc2, Wdst2, resW2, bt0, bt1, bt2,
        (int*)bnstats,
        b0, attn0, b1, attn1, b2, attn2, g0, be0, g1, be1, smallv);

    // 2-4: CSR range-assignment + parallel degree sort (fused: 3 launches)
    k_hist<<<(EE + 255) / 256, 256, 0, stream>>>(dst, cnt);
    k_binbeg<<<NBLK, 256, 0, stream>>>(cnt, binCnt, beg, total);
    k_orderscatter<<<NBLK + (EE + 255) / 256, 256, 0, stream>>>(cnt, binCnt, binPos, order,
                                                                src, dst, beg, pos, srcs);

    const int MB = (NN + 127) / 128;   // 235

    // 5-8: layer 0
    k_gemm_tiled<128, 256, 3><<<dim3(MB, 6), 256, 0, stream>>>(xc, bt0, fsb, fdb, resb);
    k_aggregate<DD, false><<<NN / 4, 256, 0, stream>>>(fsb, fdb, resb, c_attn0, c_b0,
        beg, cnt, srcs, order, hag, nullptr);
    k_bn_partial<<<MB, 256, 0, stream>>>(hag, bnstats, bnstats + 256);
    k_bn_norm<<<(int)((NF / 4 + 255) / 256), 256, 0, stream>>>(hag, bnstats, bnstats + 256,
                                                               c_g0, c_be0, hbf);

    // 9-12: layer 1 (identity residual = hbf)
    k_gemm_tiled<256, 256, 2><<<dim3(MB, 4), 256, 0, stream>>>(hbf, bt1, fsb, fdb, nullptr);
    k_aggregate<DD, false><<<NN / 4, 256, 0, stream>>>(fsb, fdb, hbf, c_attn1, c_b1,
        beg, cnt, srcs, order, hag, nullptr);
    k_bn_partial<<<MB, 256, 0, stream>>>(hag, bnstats + 512, bnstats + 768);
    k_bn_norm<<<(int)((NF / 4 + 255) / 256), 256, 0, stream>>>(hag, bnstats + 512, bnstats + 768,
                                                               c_g1, c_be1, hbf);

    // 13-14: layer 2 (packed 160-col segments) + fused head-mean/log_softmax -> d_out
    k_gemm_tiled<256, 160, 3><<<dim3(MB, 4), 256, 0, stream>>>(hbf, bt2, fsb, fdb, resb);
    k_aggregate<CC, true><<<NN / 4, 256, 0, stream>>>(fsb, fdb, resb, c_attn2, c_b2,
        beg, cnt, srcs, order, nullptr, (float*)d_out);
}